// Round 7
// baseline (921.661 us; speedup 1.0000x reference)
//
#include <hip/hip_runtime.h>
#include <hip/hip_bf16.h>

// ResidualVQVAE forward, FP32 in / FP32 out (harness reads d_out as raw fp32 --
// proven by absmax 8.255752005070376e35 not being on the bf16 grid).
// Internal math: fp32 with bf16 hi/lo splits feeding MFMA. VQ argmin runs on a
// bf16-rounded codebook (self-consistent hen); update path uses fp32 codebook.

typedef __bf16 bf16x8 __attribute__((ext_vector_type(8)));
typedef float  f32x4  __attribute__((ext_vector_type(4)));

#define MFMA16(a,b,c) __builtin_amdgcn_mfma_f32_16x16x32_bf16((a),(b),(c),0,0,0)

__device__ __forceinline__ float b2f(ushort u){ return __uint_as_float(((unsigned)u) << 16); }
__device__ __forceinline__ ushort f2b_rne(float x){
  unsigned u = __float_as_uint(x);
  return (ushort)((u + 0x7fffu + ((u >> 16) & 1u)) >> 16);
}

// ---------------- prep: fused BN scale/shift (fp32 in) ------------------------------------
__global__ void k_bnprep(const float* g1,const float* be1,const float* rm1,const float* rv1,
                         const float* g2,const float* be2,const float* rm2,const float* rv2,
                         const float* g3,const float* be3,const float* rm3,const float* rv3,
                         const float* g4,const float* be4,const float* rm4,const float* rv4,
                         float* s1,float* t1,float* s2,float* t2,
                         float* s3,float* t3,float* s4,float* t4)
{
  int t = threadIdx.x;
  if (t < 128){
    float sa = g1[t] / sqrtf(rv1[t] + 1e-5f);
    s1[t] = sa; t1[t] = be1[t] - rm1[t] * sa;
    float sb = g4[t] / sqrtf(rv4[t] + 1e-5f);
    s4[t] = sb; t4[t] = be4[t] - rm4[t] * sb;
  }
  if (t < 256){
    float sa = g2[t] / sqrtf(rv2[t] + 1e-5f);
    s2[t] = sa; t2[t] = be2[t] - rm2[t] * sa;
    float sb = g3[t] / sqrtf(rv3[t] + 1e-5f);
    s3[t] = sb; t3[t] = be3[t] - rm3[t] * sb;
  }
}

// ---------------- prep: weight swizzle fp32 -> MFMA B-frag bf16 hi (+optional lo) ---------
// B-frag for 16x16x32: lane L holds B[k = kt*32 + (L>>4)*8 + t][n = nt*16 + (L&15)], t=0..7
__global__ void k_swz(const float* __restrict__ Wm, ushort* __restrict__ Wfh,
                      ushort* __restrict__ Wfl, int K, int N){
  int gid = blockIdx.x * 256 + threadIdx.x;
  if (gid >= K * N) return;
  int k = gid / N, n = gid - k * N;
  int kt = k >> 5, kr = k & 31, nt = n >> 4, nr = n & 15;
  int lane = (kr >> 3) * 16 + nr, tt = kr & 7;
  int o = (((kt * (N >> 4)) + nt) * 64 + lane) * 8 + tt;
  float v = Wm[gid];
  ushort h = f2b_rne(v);
  Wfh[o] = h;
  if (Wfl) Wfl[o] = f2b_rne(v - b2f(h));
}

// ---------------- prep: x fp32 -> bf16 hi/lo split ----------------------------------------
__global__ void k_xsplit(const float* __restrict__ x, ushort* __restrict__ xhi, ushort* __restrict__ xlo){
  int i = blockIdx.x * 256 + threadIdx.x;
  float v = x[i];
  ushort h = f2b_rne(v);
  xhi[i] = h;
  xlo[i] = f2b_rne(v - b2f(h));
}

// ---------------- per-book: round codebook to bf16 + half-norms of ROUNDED rows -----------
__global__ __launch_bounds__(256) void k_ebook(const float* __restrict__ Ef,
                                               ushort* __restrict__ Eb, float* __restrict__ hen){
  int code = blockIdx.x * 4 + (threadIdx.x >> 6);   // 0..8191
  int L = threadIdx.x & 63;
  float2 e2 = *(const float2*)(Ef + code * 128 + L * 2);
  ushort h0 = f2b_rne(e2.x), h1 = f2b_rne(e2.y);
  *(unsigned*)(Eb + code * 128 + L * 2) = (unsigned)h0 | ((unsigned)h1 << 16);
  float eh0 = b2f(h0), eh1 = b2f(h1);
  float s = eh0 * eh0 + eh1 * eh1;
  #pragma unroll
  for (int mask = 1; mask <= 32; mask <<= 1) s += __shfl_xor(s, mask);
  if (L == 0) hen[code] = 0.5f * s;
}

// ---------------- generic small GEMM: act(bn(A@B + bias)), A split hi/lo, B hi(+lo) -------
// OUT_MODE 0: hi/lo split out; 1: split + fp32 res + zero zq; 2: fp32 only (x_hat).
template<int NN, int KK, bool HAS_BLO, bool HAS_BN, bool HAS_RELU, int OUT_MODE>
__global__ __launch_bounds__(64) void k_gemm(
    const ushort* __restrict__ Ahi, const ushort* __restrict__ Alo,
    const ushort* __restrict__ Bfh, const ushort* __restrict__ Bfl,
    const float* __restrict__ bias,
    const float* __restrict__ bns,  const float* __restrict__ bnt,
    ushort* __restrict__ Ohi, ushort* __restrict__ Olo,
    float* __restrict__ Of32, float* __restrict__ Oz)
{
  constexpr int KS = KK / 32, CT = NN / 16;
  int L = threadIdx.x;
  int qd = L >> 4, c16 = L & 15;
  int row0 = blockIdx.x * 16;

  bf16x8 ah[KS], al[KS];
  #pragma unroll
  for (int ks = 0; ks < KS; ks++){
    int off = (row0 + c16) * KK + ks * 32 + qd * 8;
    ah[ks] = *(const bf16x8*)(Ahi + off);
    al[ks] = *(const bf16x8*)(Alo + off);
  }
  #pragma unroll
  for (int ct = 0; ct < CT; ct++){
    f32x4 acc = {0.f, 0.f, 0.f, 0.f};
    #pragma unroll
    for (int ks = 0; ks < KS; ks++){
      int bo = ((ks * CT + ct) * 64 + L) * 8;
      bf16x8 bh = *(const bf16x8*)(Bfh + bo);
      acc = MFMA16(ah[ks], bh, acc);
      acc = MFMA16(al[ks], bh, acc);
      if constexpr (HAS_BLO){
        bf16x8 bl = *(const bf16x8*)(Bfl + bo);
        acc = MFMA16(ah[ks], bl, acc);
      }
    }
    int col = ct * 16 + c16;
    float bia = bias[col];
    float s = 0.f, t = 0.f;
    if constexpr (HAS_BN){ s = bns[col]; t = bnt[col]; }
    #pragma unroll
    for (int i = 0; i < 4; i++){
      int row = row0 + qd * 4 + i;
      float v = acc[i] + bia;
      if constexpr (HAS_BN) v = v * s + t;
      if constexpr (HAS_RELU) v = fmaxf(v, 0.f);
      int o = row * NN + col;
      if constexpr (OUT_MODE == 2){
        Of32[o] = v;
      } else {
        ushort h = f2b_rne(v);
        Ohi[o] = h;
        Olo[o] = f2b_rne(v - b2f(h));
        if constexpr (OUT_MODE == 1){ Of32[o] = v; Oz[o] = 0.f; }
      }
    }
  }
}

// ---------------- VQ: fused distance + argmin over one 1024-code chunk --------------------
// argmin_j ||r - e_j||^2 == argmax_j (r.e_j - 0.5||e_j||^2) on the bf16-rounded codebook.
// grid: 64 row-blocks (128 rows) x 8 chunks. Wave holds 32 rows' hi/lo A-frags in regs.
__global__ __launch_bounds__(256) void k_vq_argmin(
  const ushort* __restrict__ Rhi, const ushort* __restrict__ Rlo,
  const ushort* __restrict__ E, const float* __restrict__ hen,
  float* __restrict__ cq, int* __restrict__ cj)
{
  int rb = blockIdx.x & 63, ch = blockIdx.x >> 6;
  int wv = threadIdx.x >> 6, L = threadIdx.x & 63;
  int qd = L >> 4, c16 = L & 15;
  int row0 = rb * 128 + wv * 32;

  bf16x8 ah[2][4], al[2][4];
  #pragma unroll
  for (int t = 0; t < 2; t++){
    int r = row0 + t * 16 + c16;
    #pragma unroll
    for (int ks = 0; ks < 4; ks++){
      ah[t][ks] = *(const bf16x8*)(Rhi + r * 128 + ks * 32 + qd * 8);
      al[t][ks] = *(const bf16x8*)(Rlo + r * 128 + ks * 32 + qd * 8);
    }
  }
  float best[2][4]; int bj[2][4];
  #pragma unroll
  for (int t = 0; t < 2; t++)
    #pragma unroll
    for (int i = 0; i < 4; i++){ best[t][i] = -3.0e38f; bj[t][i] = 0; }

  int jbase = ch * 1024;
  for (int jt = 0; jt < 64; jt++){
    int jc = jbase + jt * 16 + c16;
    float h = hen[jc];
    const ushort* ep = E + jc * 128 + qd * 8;
    bf16x8 b0 = *(const bf16x8*)(ep);
    bf16x8 b1 = *(const bf16x8*)(ep + 32);
    bf16x8 b2 = *(const bf16x8*)(ep + 64);
    bf16x8 b3 = *(const bf16x8*)(ep + 96);
    #pragma unroll
    for (int t = 0; t < 2; t++){
      f32x4 acc = {0.f, 0.f, 0.f, 0.f};
      acc = MFMA16(ah[t][0], b0, acc); acc = MFMA16(al[t][0], b0, acc);
      acc = MFMA16(ah[t][1], b1, acc); acc = MFMA16(al[t][1], b1, acc);
      acc = MFMA16(ah[t][2], b2, acc); acc = MFMA16(al[t][2], b2, acc);
      acc = MFMA16(ah[t][3], b3, acc); acc = MFMA16(al[t][3], b3, acc);
      #pragma unroll
      for (int i = 0; i < 4; i++){
        float qv = acc[i] - h;
        if (qv > best[t][i]){ best[t][i] = qv; bj[t][i] = jc; }  // strict >: first index wins
      }
    }
  }
  #pragma unroll
  for (int mask = 1; mask <= 8; mask <<= 1){
    #pragma unroll
    for (int t = 0; t < 2; t++)
      #pragma unroll
      for (int i = 0; i < 4; i++){
        float ob = __shfl_xor(best[t][i], mask);
        int   oj = __shfl_xor(bj[t][i], mask);
        if (ob > best[t][i] || (ob == best[t][i] && oj < bj[t][i])){ best[t][i] = ob; bj[t][i] = oj; }
      }
  }
  if (c16 == 0){
    #pragma unroll
    for (int t = 0; t < 2; t++)
      #pragma unroll
      for (int i = 0; i < 4; i++){
        int r = row0 + t * 16 + qd * 4 + i;
        cq[r * 8 + ch] = best[t][i];
        cj[r * 8 + ch] = bj[t][i];
      }
  }
}

// ---------------- VQ: combine chunk candidates, emit fp32 res_s/ce_s, update residual -----
__global__ __launch_bounds__(256) void k_vq_update(
  const float* __restrict__ cq, const int* __restrict__ cj,
  const float* __restrict__ Ef,
  float* __restrict__ res, float* __restrict__ zq,
  ushort* __restrict__ rhi, ushort* __restrict__ rlo,
  float* __restrict__ res_s, float* __restrict__ ce_s)
{
  int row = blockIdx.x * 4 + (threadIdx.x >> 6);
  int L = threadIdx.x & 63;
  float bq = cq[row * 8]; int bi = cj[row * 8];
  #pragma unroll
  for (int c = 1; c < 8; c++){
    float qc = cq[row * 8 + c]; int jc = cj[row * 8 + c];
    if (qc > bq){ bq = qc; bi = jc; }
  }
  int o = row * 128 + L * 2;
  float2 ce = *(const float2*)(Ef + bi * 128 + L * 2);   // fp32 codebook row
  float2 r2 = *(const float2*)(res + o);
  *(float2*)(res_s + o) = r2;
  *(float2*)(ce_s + o) = ce;
  float rn0 = r2.x - ce.x, rn1 = r2.y - ce.y;
  res[o] = rn0; res[o + 1] = rn1;
  zq[o] += ce.x; zq[o + 1] += ce.y;
  ushort h0 = f2b_rne(rn0), h1 = f2b_rne(rn1);
  *(unsigned*)(rhi + o) = (unsigned)h0 | ((unsigned)h1 << 16);
  ushort l0 = f2b_rne(rn0 - b2f(h0)), l1 = f2b_rne(rn1 - b2f(h1));
  *(unsigned*)(rlo + o) = (unsigned)l0 | ((unsigned)l1 << 16);
}

// ---------------- di = zq (STE forward), split for decoder GEMM ---------------------------
__global__ void k_di(const float* __restrict__ zq, ushort* __restrict__ rhi, ushort* __restrict__ rlo){
  int i = blockIdx.x * 256 + threadIdx.x;
  float v = zq[i];
  ushort h = f2b_rne(v);
  rhi[i] = h;
  rlo[i] = f2b_rne(v - b2f(h));
}

extern "C" void kernel_launch(void* const* d_in, const int* in_sizes, int n_in,
                              void* d_out, int out_size, void* d_ws, size_t ws_size,
                              hipStream_t stream)
{
  const float* x   = (const float*)d_in[0];
  const float* W1  = (const float*)d_in[1];
  const float* b1  = (const float*)d_in[2];
  const float* g1  = (const float*)d_in[3];
  const float* be1 = (const float*)d_in[4];
  const float* rm1 = (const float*)d_in[5];
  const float* rv1 = (const float*)d_in[6];
  const float* W2  = (const float*)d_in[7];
  const float* b2  = (const float*)d_in[8];
  const float* g2  = (const float*)d_in[9];
  const float* be2 = (const float*)d_in[10];
  const float* rm2 = (const float*)d_in[11];
  const float* rv2 = (const float*)d_in[12];
  const float* W3  = (const float*)d_in[13];
  const float* b3  = (const float*)d_in[14];
  const float* CB  = (const float*)d_in[15];
  const float* W4  = (const float*)d_in[16];
  const float* b4  = (const float*)d_in[17];
  const float* g3  = (const float*)d_in[18];
  const float* be3 = (const float*)d_in[19];
  const float* rm3 = (const float*)d_in[20];
  const float* rv3 = (const float*)d_in[21];
  const float* W5  = (const float*)d_in[22];
  const float* b5  = (const float*)d_in[23];
  const float* g4  = (const float*)d_in[24];
  const float* be4 = (const float*)d_in[25];
  const float* rm4 = (const float*)d_in[26];
  const float* rv4 = (const float*)d_in[27];
  const float* W6  = (const float*)d_in[28];
  const float* b6  = (const float*)d_in[29];

  char* w = (char*)d_ws;                       // total ~24.6 MiB
  // Eb and cq/cj alias the h1 region: h1 written by enc GEMM-1, consumed by enc GEMM-2,
  // dead during VQ; decoder GEMM-2 rewrites h1 after VQ is done.
  ushort* Eb   = (ushort*)(w + 0);             // per-book bf16 codebook, 2 MiB
  float*  cq   = (float*) (w + 2097152);       // 8192x8, 256 KiB
  int*    cj   = (int*)   (w + 2359296);       // 8192x8, 256 KiB
  ushort* h1hi = (ushort*)(w + 0);             // 8192x128 bf16, 2 MiB
  ushort* h1lo = (ushort*)(w + 2097152);       // 2 MiB
  ushort* h2hi = (ushort*)(w + 4194304);       // 8192x256 bf16, 4 MiB
  ushort* h2lo = (ushort*)(w + 8388608);       // 4 MiB
  ushort* rhi  = (ushort*)(w + 12582912);      // residual split, 2 MiB
  ushort* rlo  = (ushort*)(w + 14680064);      // 2 MiB
  // res/zq alias xhi/xlo: x consumed by enc GEMM-1 before res/zq written by enc GEMM-3.
  ushort* xhi  = (ushort*)(w + 16777216);      // 8192x256 bf16, 4 MiB
  ushort* xlo  = (ushort*)(w + 20971520);      // 4 MiB
  float*  res  = (float*) (w + 16777216);      // fp32 residual, 4 MiB
  float*  zq   = (float*) (w + 20971520);      // fp32 ce accumulator, 4 MiB
  float*  hen  = (float*) (w + 25165824);      // per-book half-norms, 32 KiB
  float*  s1   = (float*) (w + 25198592);
  float*  t1   = (float*) (w + 25199104);
  float*  s2   = (float*) (w + 25199616);
  float*  t2   = (float*) (w + 25200640);
  float*  s3   = (float*) (w + 25201664);
  float*  t3   = (float*) (w + 25202688);
  float*  s4   = (float*) (w + 25203712);
  float*  t4   = (float*) (w + 25204224);
  ushort* W1fh = (ushort*)(w + 25204736);
  ushort* W2fh = (ushort*)(w + 25270272);
  ushort* W3fh = (ushort*)(w + 25335808);
  ushort* W4fh = (ushort*)(w + 25401344);
  ushort* W5fh = (ushort*)(w + 25466880);
  ushort* W6fh = (ushort*)(w + 25532416);
  ushort* W1fl = (ushort*)(w + 25597952);
  ushort* W2fl = (ushort*)(w + 25663488);
  ushort* W3fl = (ushort*)(w + 25729024);      // end 25794560 (~24.6 MiB)

  float* xhat  = (float*)d_out;                // [8192,256] fp32
  float* res_s = xhat + 2097152;               // [8,8192,128] fp32
  float* ce_s  = res_s + 8388608;              // [8,8192,128] fp32

  k_bnprep<<<1, 256, 0, stream>>>(g1,be1,rm1,rv1, g2,be2,rm2,rv2,
                                  g3,be3,rm3,rv3, g4,be4,rm4,rv4,
                                  s1,t1,s2,t2,s3,t3,s4,t4);
  k_swz<<<128, 256, 0, stream>>>(W1, W1fh, W1fl, 256, 128);
  k_swz<<<128, 256, 0, stream>>>(W2, W2fh, W2fl, 128, 256);
  k_swz<<<128, 256, 0, stream>>>(W3, W3fh, W3fl, 256, 128);
  k_swz<<<128, 256, 0, stream>>>(W4, W4fh, nullptr, 128, 256);
  k_swz<<<128, 256, 0, stream>>>(W5, W5fh, nullptr, 256, 128);
  k_swz<<<128, 256, 0, stream>>>(W6, W6fh, nullptr, 128, 256);
  k_xsplit<<<8192, 256, 0, stream>>>(x, xhi, xlo);

  // encoder (A split hi/lo, B split hi/lo for argmin-path precision)
  k_gemm<128,256,true,true,true,0><<<512,64,0,stream>>>(xhi, xlo, W1fh, W1fl, b1, s1, t1, h1hi, h1lo, nullptr, nullptr);
  k_gemm<256,128,true,true,true,0><<<512,64,0,stream>>>(h1hi, h1lo, W2fh, W2fl, b2, s2, t2, h2hi, h2lo, nullptr, nullptr);
  k_gemm<128,256,true,false,false,1><<<512,64,0,stream>>>(h2hi, h2lo, W3fh, W3fl, b3, nullptr, nullptr, rhi, rlo, res, zq);

  // residual VQ over 8 books
  for (int m = 0; m < 8; m++){
    const float* Ef = CB + (size_t)m * 8192 * 128;
    k_ebook<<<2048, 256, 0, stream>>>(Ef, Eb, hen);
    k_vq_argmin<<<512, 256, 0, stream>>>(rhi, rlo, Eb, hen, cq, cj);
    k_vq_update<<<2048, 256, 0, stream>>>(cq, cj, Ef, res, zq, rhi, rlo,
                                          res_s + (size_t)m * 1048576,
                                          ce_s  + (size_t)m * 1048576);
  }
  k_di<<<4096, 256, 0, stream>>>(zq, rhi, rlo);

  // decoder (B hi only; |x_hat| ~ 0.06, threshold 2.5e-3)
  k_gemm<256,128,false,true,true,0><<<512,64,0,stream>>>(rhi, rlo, W4fh, nullptr, b4, s3, t3, h2hi, h2lo, nullptr, nullptr);
  k_gemm<128,256,false,true,true,0><<<512,64,0,stream>>>(h2hi, h2lo, W5fh, nullptr, b5, s4, t4, h1hi, h1lo, nullptr, nullptr);
  k_gemm<256,128,false,false,false,2><<<512,64,0,stream>>>(h1hi, h1lo, W6fh, nullptr, b6, nullptr, nullptr, nullptr, nullptr, xhat, nullptr);
}

// Round 8
// 671.953 us; speedup vs baseline: 1.3716x; 1.3716x over previous
//
#include <hip/hip_runtime.h>
#include <hip/hip_bf16.h>

// ResidualVQVAE forward, FP32 in / FP32 out.
// R8: k_vq_argmin rebuilt around an LDS-staged, XOR-swizzled shared E tile
// (64 codes x 128 dims bf16, 16 KiB) shared by all 4 waves of a block; 16 code
// chunks (1024 WGs, 4 blocks/CU at launch_bounds(256,4)). Rest = R7 (proven).

typedef __bf16 bf16x8 __attribute__((ext_vector_type(8)));
typedef float  f32x4  __attribute__((ext_vector_type(4)));

#define MFMA16(a,b,c) __builtin_amdgcn_mfma_f32_16x16x32_bf16((a),(b),(c),0,0,0)

__device__ __forceinline__ float b2f(ushort u){ return __uint_as_float(((unsigned)u) << 16); }
__device__ __forceinline__ ushort f2b_rne(float x){
  unsigned u = __float_as_uint(x);
  return (ushort)((u + 0x7fffu + ((u >> 16) & 1u)) >> 16);
}

// ---------------- prep: fused BN scale/shift (fp32 in) ------------------------------------
__global__ void k_bnprep(const float* g1,const float* be1,const float* rm1,const float* rv1,
                         const float* g2,const float* be2,const float* rm2,const float* rv2,
                         const float* g3,const float* be3,const float* rm3,const float* rv3,
                         const float* g4,const float* be4,const float* rm4,const float* rv4,
                         float* s1,float* t1,float* s2,float* t2,
                         float* s3,float* t3,float* s4,float* t4)
{
  int t = threadIdx.x;
  if (t < 128){
    float sa = g1[t] / sqrtf(rv1[t] + 1e-5f);
    s1[t] = sa; t1[t] = be1[t] - rm1[t] * sa;
    float sb = g4[t] / sqrtf(rv4[t] + 1e-5f);
    s4[t] = sb; t4[t] = be4[t] - rm4[t] * sb;
  }
  if (t < 256){
    float sa = g2[t] / sqrtf(rv2[t] + 1e-5f);
    s2[t] = sa; t2[t] = be2[t] - rm2[t] * sa;
    float sb = g3[t] / sqrtf(rv3[t] + 1e-5f);
    s3[t] = sb; t3[t] = be3[t] - rm3[t] * sb;
  }
}

// ---------------- prep: weight swizzle fp32 -> MFMA B-frag bf16 hi (+optional lo) ---------
__global__ void k_swz(const float* __restrict__ Wm, ushort* __restrict__ Wfh,
                      ushort* __restrict__ Wfl, int K, int N){
  int gid = blockIdx.x * 256 + threadIdx.x;
  if (gid >= K * N) return;
  int k = gid / N, n = gid - k * N;
  int kt = k >> 5, kr = k & 31, nt = n >> 4, nr = n & 15;
  int lane = (kr >> 3) * 16 + nr, tt = kr & 7;
  int o = (((kt * (N >> 4)) + nt) * 64 + lane) * 8 + tt;
  float v = Wm[gid];
  ushort h = f2b_rne(v);
  Wfh[o] = h;
  if (Wfl) Wfl[o] = f2b_rne(v - b2f(h));
}

// ---------------- prep: x fp32 -> bf16 hi/lo split ----------------------------------------
__global__ void k_xsplit(const float* __restrict__ x, ushort* __restrict__ xhi, ushort* __restrict__ xlo){
  int i = blockIdx.x * 256 + threadIdx.x;
  float v = x[i];
  ushort h = f2b_rne(v);
  xhi[i] = h;
  xlo[i] = f2b_rne(v - b2f(h));
}

// ---------------- per-book: round codebook to bf16 + half-norms of ROUNDED rows -----------
__global__ __launch_bounds__(256) void k_ebook(const float* __restrict__ Ef,
                                               ushort* __restrict__ Eb, float* __restrict__ hen){
  int code = blockIdx.x * 4 + (threadIdx.x >> 6);   // 0..8191
  int L = threadIdx.x & 63;
  float2 e2 = *(const float2*)(Ef + code * 128 + L * 2);
  ushort h0 = f2b_rne(e2.x), h1 = f2b_rne(e2.y);
  *(unsigned*)(Eb + code * 128 + L * 2) = (unsigned)h0 | ((unsigned)h1 << 16);
  float eh0 = b2f(h0), eh1 = b2f(h1);
  float s = eh0 * eh0 + eh1 * eh1;
  #pragma unroll
  for (int mask = 1; mask <= 32; mask <<= 1) s += __shfl_xor(s, mask);
  if (L == 0) hen[code] = 0.5f * s;
}

// ---------------- generic small GEMM: act(bn(A@B + bias)), A split hi/lo, B hi(+lo) -------
template<int NN, int KK, bool HAS_BLO, bool HAS_BN, bool HAS_RELU, int OUT_MODE>
__global__ __launch_bounds__(64) void k_gemm(
    const ushort* __restrict__ Ahi, const ushort* __restrict__ Alo,
    const ushort* __restrict__ Bfh, const ushort* __restrict__ Bfl,
    const float* __restrict__ bias,
    const float* __restrict__ bns,  const float* __restrict__ bnt,
    ushort* __restrict__ Ohi, ushort* __restrict__ Olo,
    float* __restrict__ Of32, float* __restrict__ Oz)
{
  constexpr int KS = KK / 32, CT = NN / 16;
  int L = threadIdx.x;
  int qd = L >> 4, c16 = L & 15;
  int row0 = blockIdx.x * 16;

  bf16x8 ah[KS], al[KS];
  #pragma unroll
  for (int ks = 0; ks < KS; ks++){
    int off = (row0 + c16) * KK + ks * 32 + qd * 8;
    ah[ks] = *(const bf16x8*)(Ahi + off);
    al[ks] = *(const bf16x8*)(Alo + off);
  }
  #pragma unroll
  for (int ct = 0; ct < CT; ct++){
    f32x4 acc = {0.f, 0.f, 0.f, 0.f};
    #pragma unroll
    for (int ks = 0; ks < KS; ks++){
      int bo = ((ks * CT + ct) * 64 + L) * 8;
      bf16x8 bh = *(const bf16x8*)(Bfh + bo);
      acc = MFMA16(ah[ks], bh, acc);
      acc = MFMA16(al[ks], bh, acc);
      if constexpr (HAS_BLO){
        bf16x8 bl = *(const bf16x8*)(Bfl + bo);
        acc = MFMA16(ah[ks], bl, acc);
      }
    }
    int col = ct * 16 + c16;
    float bia = bias[col];
    float s = 0.f, t = 0.f;
    if constexpr (HAS_BN){ s = bns[col]; t = bnt[col]; }
    #pragma unroll
    for (int i = 0; i < 4; i++){
      int row = row0 + qd * 4 + i;
      float v = acc[i] + bia;
      if constexpr (HAS_BN) v = v * s + t;
      if constexpr (HAS_RELU) v = fmaxf(v, 0.f);
      int o = row * NN + col;
      if constexpr (OUT_MODE == 2){
        Of32[o] = v;
      } else {
        ushort h = f2b_rne(v);
        Ohi[o] = h;
        Olo[o] = f2b_rne(v - b2f(h));
        if constexpr (OUT_MODE == 1){ Of32[o] = v; Oz[o] = 0.f; }
      }
    }
  }
}

// ---------------- VQ: fused distance + argmin, LDS-staged E tiles -------------------------
// argmax_j (r.e_j - 0.5||e_j||^2) on bf16-rounded codebook.
// grid: 64 row-blocks (128 rows) x 16 chunks (512 codes). Per block: loop 8 tiles of
// 64 codes; tile staged in LDS with XOR-16B swizzle (pos = chunk ^ (row&15)) -> both
// staging writes and fragment ds_reads hit uniform 8-lane/4-bank windows (conflict-free).
__global__ __launch_bounds__(256, 4) void k_vq_argmin(
  const ushort* __restrict__ Rhi, const ushort* __restrict__ Rlo,
  const ushort* __restrict__ Eb, const float* __restrict__ hen,
  float* __restrict__ cq, int* __restrict__ cj)
{
  __shared__ __align__(16) ushort etile[8192];   // 64 codes x 128 dims bf16, swizzled
  __shared__ float henl[64];
  int rb = blockIdx.x & 63, ch = blockIdx.x >> 6;
  int tid = threadIdx.x;
  int wv = tid >> 6, L = tid & 63;
  int qd = L >> 4, c16 = L & 15;
  int row0 = rb * 128 + wv * 32;

  // resident A fragments: 32 rows hi+lo (64 VGPRs)
  bf16x8 ah[2][4], al[2][4];
  #pragma unroll
  for (int t = 0; t < 2; t++){
    int r = row0 + t * 16 + c16;
    #pragma unroll
    for (int ks = 0; ks < 4; ks++){
      ah[t][ks] = *(const bf16x8*)(Rhi + r * 128 + ks * 32 + qd * 8);
      al[t][ks] = *(const bf16x8*)(Rlo + r * 128 + ks * 32 + qd * 8);
    }
  }
  float best[2][4]; int bj[2][4];
  #pragma unroll
  for (int t = 0; t < 2; t++)
    #pragma unroll
    for (int i = 0; i < 4; i++){ best[t][i] = -3.0e38f; bj[t][i] = 0; }

  // staging source offset (ushorts): row (tid>>4) of each 16-row pass, chunk (tid&15)
  // fetches global 16B-chunk ((tid&15) ^ (tid>>4)) of that row
  int gsoff = (tid >> 4) * 128 + (((tid & 15) ^ (tid >> 4)) * 8);
  int cb0 = ch * 512;                           // chunk code base

  for (int t = 0; t < 8; ++t){
    int tb = cb0 + t * 64;                      // tile code base
    const ushort* src = Eb + (size_t)tb * 128;
    f32x4 v0 = *(const f32x4*)(src + 0 * 2048 + gsoff);
    f32x4 v1 = *(const f32x4*)(src + 1 * 2048 + gsoff);
    f32x4 v2 = *(const f32x4*)(src + 2 * 2048 + gsoff);
    f32x4 v3 = *(const f32x4*)(src + 3 * 2048 + gsoff);
    *(f32x4*)(etile + 0 * 2048 + tid * 8) = v0;
    *(f32x4*)(etile + 1 * 2048 + tid * 8) = v1;
    *(f32x4*)(etile + 2 * 2048 + tid * 8) = v2;
    *(f32x4*)(etile + 3 * 2048 + tid * 8) = v3;
    if (tid < 64) henl[tid] = hen[tb + tid];
    __syncthreads();

    #pragma unroll
    for (int s = 0; s < 4; ++s){
      float h = henl[s * 16 + c16];
      const ushort* eb = etile + (s * 16 + c16) * 128;
      bf16x8 b0 = *(const bf16x8*)(eb + (((0 * 4 + qd) ^ c16) * 8));
      bf16x8 b1 = *(const bf16x8*)(eb + (((1 * 4 + qd) ^ c16) * 8));
      bf16x8 b2 = *(const bf16x8*)(eb + (((2 * 4 + qd) ^ c16) * 8));
      bf16x8 b3 = *(const bf16x8*)(eb + (((3 * 4 + qd) ^ c16) * 8));
      int jc = tb + s * 16 + c16;
      #pragma unroll
      for (int tt = 0; tt < 2; tt++){
        f32x4 acc = {0.f, 0.f, 0.f, 0.f};
        acc = MFMA16(ah[tt][0], b0, acc); acc = MFMA16(al[tt][0], b0, acc);
        acc = MFMA16(ah[tt][1], b1, acc); acc = MFMA16(al[tt][1], b1, acc);
        acc = MFMA16(ah[tt][2], b2, acc); acc = MFMA16(al[tt][2], b2, acc);
        acc = MFMA16(ah[tt][3], b3, acc); acc = MFMA16(al[tt][3], b3, acc);
        #pragma unroll
        for (int i = 0; i < 4; i++){
          float qv = acc[i] - h;
          if (qv > best[tt][i]){ best[tt][i] = qv; bj[tt][i] = jc; }
        }
      }
    }
    __syncthreads();
  }
  // cross-lane reduce over the 16 code-columns, ties -> smaller j
  #pragma unroll
  for (int mask = 1; mask <= 8; mask <<= 1){
    #pragma unroll
    for (int t = 0; t < 2; t++)
      #pragma unroll
      for (int i = 0; i < 4; i++){
        float ob = __shfl_xor(best[t][i], mask);
        int   oj = __shfl_xor(bj[t][i], mask);
        if (ob > best[t][i] || (ob == best[t][i] && oj < bj[t][i])){ best[t][i] = ob; bj[t][i] = oj; }
      }
  }
  if (c16 == 0){
    #pragma unroll
    for (int t = 0; t < 2; t++)
      #pragma unroll
      for (int i = 0; i < 4; i++){
        int r = row0 + t * 16 + qd * 4 + i;
        cq[r * 16 + ch] = best[t][i];
        cj[r * 16 + ch] = bj[t][i];
      }
  }
}

// ---------------- VQ: combine 16 chunk candidates, emit fp32 res_s/ce_s, update -----------
__global__ __launch_bounds__(256) void k_vq_update(
  const float* __restrict__ cq, const int* __restrict__ cj,
  const float* __restrict__ Ef,
  float* __restrict__ res, float* __restrict__ zq,
  ushort* __restrict__ rhi, ushort* __restrict__ rlo,
  float* __restrict__ res_s, float* __restrict__ ce_s)
{
  int row = blockIdx.x * 4 + (threadIdx.x >> 6);
  int L = threadIdx.x & 63;
  int c = L & 15;
  float bq = cq[row * 16 + c]; int bi = cj[row * 16 + c];
  #pragma unroll
  for (int mask = 1; mask <= 8; mask <<= 1){
    float ob = __shfl_xor(bq, mask);
    int   oj = __shfl_xor(bi, mask);
    if (ob > bq || (ob == bq && oj < bi)){ bq = ob; bi = oj; }
  }
  // lanes within each 16-group agree; all groups identical
  int o = row * 128 + L * 2;
  float2 ce = *(const float2*)(Ef + bi * 128 + L * 2);   // fp32 codebook row
  float2 r2 = *(const float2*)(res + o);
  *(float2*)(res_s + o) = r2;
  *(float2*)(ce_s + o) = ce;
  float rn0 = r2.x - ce.x, rn1 = r2.y - ce.y;
  res[o] = rn0; res[o + 1] = rn1;
  zq[o] += ce.x; zq[o + 1] += ce.y;
  ushort h0 = f2b_rne(rn0), h1 = f2b_rne(rn1);
  *(unsigned*)(rhi + o) = (unsigned)h0 | ((unsigned)h1 << 16);
  ushort l0 = f2b_rne(rn0 - b2f(h0)), l1 = f2b_rne(rn1 - b2f(h1));
  *(unsigned*)(rlo + o) = (unsigned)l0 | ((unsigned)l1 << 16);
}

// ---------------- di = zq (STE forward), split for decoder GEMM ---------------------------
__global__ void k_di(const float* __restrict__ zq, ushort* __restrict__ rhi, ushort* __restrict__ rlo){
  int i = blockIdx.x * 256 + threadIdx.x;
  float v = zq[i];
  ushort h = f2b_rne(v);
  rhi[i] = h;
  rlo[i] = f2b_rne(v - b2f(h));
}

extern "C" void kernel_launch(void* const* d_in, const int* in_sizes, int n_in,
                              void* d_out, int out_size, void* d_ws, size_t ws_size,
                              hipStream_t stream)
{
  const float* x   = (const float*)d_in[0];
  const float* W1  = (const float*)d_in[1];
  const float* b1  = (const float*)d_in[2];
  const float* g1  = (const float*)d_in[3];
  const float* be1 = (const float*)d_in[4];
  const float* rm1 = (const float*)d_in[5];
  const float* rv1 = (const float*)d_in[6];
  const float* W2  = (const float*)d_in[7];
  const float* b2  = (const float*)d_in[8];
  const float* g2  = (const float*)d_in[9];
  const float* be2 = (const float*)d_in[10];
  const float* rm2 = (const float*)d_in[11];
  const float* rv2 = (const float*)d_in[12];
  const float* W3  = (const float*)d_in[13];
  const float* b3  = (const float*)d_in[14];
  const float* CB  = (const float*)d_in[15];
  const float* W4  = (const float*)d_in[16];
  const float* b4  = (const float*)d_in[17];
  const float* g3  = (const float*)d_in[18];
  const float* be3 = (const float*)d_in[19];
  const float* rm3 = (const float*)d_in[20];
  const float* rv3 = (const float*)d_in[21];
  const float* W5  = (const float*)d_in[22];
  const float* b5  = (const float*)d_in[23];
  const float* g4  = (const float*)d_in[24];
  const float* be4 = (const float*)d_in[25];
  const float* rm4 = (const float*)d_in[26];
  const float* rv4 = (const float*)d_in[27];
  const float* W6  = (const float*)d_in[28];
  const float* b6  = (const float*)d_in[29];

  char* w = (char*)d_ws;                       // total ~24.6 MiB
  // Eb + cq/cj alias the h1 region (dead during VQ; decoder GEMM-2 rewrites h1 after).
  ushort* Eb   = (ushort*)(w + 0);             // per-book bf16 codebook, 2 MiB
  float*  cq   = (float*) (w + 2097152);       // 8192x16, 512 KiB
  int*    cj   = (int*)   (w + 2621440);       // 8192x16, 512 KiB (ends 3 MiB < 4 MiB)
  ushort* h1hi = (ushort*)(w + 0);             // 8192x128 bf16, 2 MiB
  ushort* h1lo = (ushort*)(w + 2097152);       // 2 MiB
  ushort* h2hi = (ushort*)(w + 4194304);       // 8192x256 bf16, 4 MiB
  ushort* h2lo = (ushort*)(w + 8388608);       // 4 MiB
  ushort* rhi  = (ushort*)(w + 12582912);      // residual split, 2 MiB
  ushort* rlo  = (ushort*)(w + 14680064);      // 2 MiB
  // res/zq alias xhi/xlo (x consumed by enc GEMM-1 before res/zq written).
  ushort* xhi  = (ushort*)(w + 16777216);      // 4 MiB
  ushort* xlo  = (ushort*)(w + 20971520);      // 4 MiB
  float*  res  = (float*) (w + 16777216);
  float*  zq   = (float*) (w + 20971520);
  float*  hen  = (float*) (w + 25165824);      // per-book half-norms, 32 KiB
  float*  s1   = (float*) (w + 25198592);
  float*  t1   = (float*) (w + 25199104);
  float*  s2   = (float*) (w + 25199616);
  float*  t2   = (float*) (w + 25200640);
  float*  s3   = (float*) (w + 25201664);
  float*  t3   = (float*) (w + 25202688);
  float*  s4   = (float*) (w + 25203712);
  float*  t4   = (float*) (w + 25204224);
  ushort* W1fh = (ushort*)(w + 25204736);
  ushort* W2fh = (ushort*)(w + 25270272);
  ushort* W3fh = (ushort*)(w + 25335808);
  ushort* W4fh = (ushort*)(w + 25401344);
  ushort* W5fh = (ushort*)(w + 25466880);
  ushort* W6fh = (ushort*)(w + 25532416);
  ushort* W1fl = (ushort*)(w + 25597952);
  ushort* W2fl = (ushort*)(w + 25663488);
  ushort* W3fl = (ushort*)(w + 25729024);      // end ~24.6 MiB

  float* xhat  = (float*)d_out;                // [8192,256] fp32
  float* res_s = xhat + 2097152;               // [8,8192,128] fp32
  float* ce_s  = res_s + 8388608;              // [8,8192,128] fp32

  k_bnprep<<<1, 256, 0, stream>>>(g1,be1,rm1,rv1, g2,be2,rm2,rv2,
                                  g3,be3,rm3,rv3, g4,be4,rm4,rv4,
                                  s1,t1,s2,t2,s3,t3,s4,t4);
  k_swz<<<128, 256, 0, stream>>>(W1, W1fh, W1fl, 256, 128);
  k_swz<<<128, 256, 0, stream>>>(W2, W2fh, W2fl, 128, 256);
  k_swz<<<128, 256, 0, stream>>>(W3, W3fh, W3fl, 256, 128);
  k_swz<<<128, 256, 0, stream>>>(W4, W4fh, nullptr, 128, 256);
  k_swz<<<128, 256, 0, stream>>>(W5, W5fh, nullptr, 256, 128);
  k_swz<<<128, 256, 0, stream>>>(W6, W6fh, nullptr, 128, 256);
  k_xsplit<<<8192, 256, 0, stream>>>(x, xhi, xlo);

  // encoder
  k_gemm<128,256,true,true,true,0><<<512,64,0,stream>>>(xhi, xlo, W1fh, W1fl, b1, s1, t1, h1hi, h1lo, nullptr, nullptr);
  k_gemm<256,128,true,true,true,0><<<512,64,0,stream>>>(h1hi, h1lo, W2fh, W2fl, b2, s2, t2, h2hi, h2lo, nullptr, nullptr);
  k_gemm<128,256,true,false,false,1><<<512,64,0,stream>>>(h2hi, h2lo, W3fh, W3fl, b3, nullptr, nullptr, rhi, rlo, res, zq);

  // residual VQ over 8 books
  for (int m = 0; m < 8; m++){
    const float* Ef = CB + (size_t)m * 8192 * 128;
    k_ebook<<<2048, 256, 0, stream>>>(Ef, Eb, hen);
    k_vq_argmin<<<1024, 256, 0, stream>>>(rhi, rlo, Eb, hen, cq, cj);
    k_vq_update<<<2048, 256, 0, stream>>>(cq, cj, Ef, res, zq, rhi, rlo,
                                          res_s + (size_t)m * 1048576,
                                          ce_s  + (size_t)m * 1048576);
  }
  k_di<<<4096, 256, 0, stream>>>(zq, rhi, rlo);

  // decoder
  k_gemm<256,128,false,true,true,0><<<512,64,0,stream>>>(rhi, rlo, W4fh, nullptr, b4, s3, t3, h2hi, h2lo, nullptr, nullptr);
  k_gemm<128,256,false,true,true,0><<<512,64,0,stream>>>(h2hi, h2lo, W5fh, nullptr, b5, s4, t4, h1hi, h1lo, nullptr, nullptr);
  k_gemm<256,128,false,false,false,2><<<512,64,0,stream>>>(h1hi, h1lo, W6fh, nullptr, b6, nullptr, nullptr, nullptr, nullptr, xhat, nullptr);
}